// Round 19
// baseline (29.140 us; speedup 1.0000x reference)
//
#include <hip/hip_runtime.h>
#include <hip/hip_fp16.h>

// DAA autoencoder — R19: R18 register-blocked pipeline + dual-path addends
// (LDS broadcast for half the rows, wave-uniform s_load from pre-expanded
// global for the other half), 256-i slices (7 barriers vs 11), and
// packed-pair partial publish/merge (b32, pk_min/max merges 2 rows at once).
//   layer0: h[b][o]   = min_i ( sel0[o][i] ? x[b][i] : 2.0f )
//   layer1: out[b][o] = max_i ( sel1[o][i] ? h[b][i] : -1.0f )
// B=256, IN=1024, HID=512.
//
// Accuracy: identical per-edge values to R15-R18 (f32->f16 RN, +/-inf
// addends, exact offsets; min/max order-independent) => absmax 1.22e-4.

#define H_PINF 0x7C00u
#define H_NINF 0xFC00u

__device__ __forceinline__ unsigned pk_add(unsigned a, unsigned b) {
    unsigned r; asm("v_pk_add_f16 %0, %1, %2" : "=v"(r) : "v"(a), "v"(b)); return r;
}
__device__ __forceinline__ unsigned pk_min(unsigned a, unsigned b) {
    unsigned r; asm("v_pk_min_f16 %0, %1, %2" : "=v"(r) : "v"(a), "v"(b)); return r;
}
__device__ __forceinline__ unsigned pk_max(unsigned a, unsigned b) {
    unsigned r; asm("v_pk_max_f16 %0, %1, %2" : "=v"(r) : "v"(a), "v"(b)); return r;
}
__device__ __forceinline__ unsigned hpk(float a, float b) {
    return (unsigned)__half_as_ushort(__float2half(a))
         | ((unsigned)__half_as_ushort(__float2half(b)) << 16);
}
__device__ __forceinline__ float h2f(unsigned short u) {
    __half h = *reinterpret_cast<__half*>(&u);
    return __half2float(h);
}
__device__ __forceinline__ unsigned selpk(int a, int b, unsigned inf) {
    return (a ? 0u : inf) | ((b ? 0u : inf) << 16);
}

// ===== pack: expand the scalar-path halves of sel into f16 addends =======
// a0h row jr=(j*4+r): sel0 row j*8+4+r  (j=0..63, r=0..3), 512 words/row.
// a1h row jr=(j2*8+r): sel1 row j2*16+8+r (j2=0..63, r=0..7), 256 words/row.
__global__ __launch_bounds__(256) void pack_sc(
    const int* __restrict__ sel0, const int* __restrict__ sel1,
    unsigned* __restrict__ a0h, unsigned* __restrict__ a1h)
{
    const int t = blockIdx.x * 256 + threadIdx.x;   // 0..65535
    {
        const int jr = t >> 8, i4 = t & 255;
        const int srow = (jr >> 2) * 8 + 4 + (jr & 3);
        const int4 v = ((const int4*)sel0)[(size_t)srow * 256 + i4];
        unsigned* d = &a0h[(size_t)jr * 512 + i4 * 2];
        d[0] = selpk(v.x, v.y, H_PINF);
        d[1] = selpk(v.z, v.w, H_PINF);
    }
    {
        const int jr = t >> 7, i4 = t & 127;
        const int srow = (jr >> 3) * 16 + 8 + (jr & 7);
        const int4 v = ((const int4*)sel1)[(size_t)srow * 128 + i4];
        unsigned* d = &a1h[(size_t)jr * 256 + i4 * 2];
        d[0] = selpk(v.x, v.y, H_NINF);
        d[1] = selpk(v.z, v.w, H_NINF);
    }
}

// ===== L0: x + sel0 -> hS[4][64][64] uint4 f16 slabs =====================
// block = (j = o-oct) x (bch); 16 waves. Wave s owns octs 2s,2s+1 of each
// 256-i slice; acc rows 0..3 = 8j..8j+3 (LDS addends), 4..7 = scalar path.
__global__ __launch_bounds__(1024) void daa_l0(
    const float* __restrict__ x, const int* __restrict__ sel0,
    const unsigned* __restrict__ a0h, uint4* __restrict__ hS)
{
    __shared__ unsigned aW[4 * 512];            // rows 8j..8j+3, 8 KB
    __shared__ uint4 xL[2][32 * 65];            // 256-i slice dbuf, 2x33 KB
    __shared__ unsigned red32[16 * 4 * 64];     // packed pairs, 16 KB
    __shared__ unsigned mrg32[4 * 64];          // merged pairs, 1 KB

    const int tid  = threadIdx.x;
    const int lane = tid & 63;
    const int s    = __builtin_amdgcn_readfirstlane(tid >> 6);
    const int bch  = blockIdx.x & 3;
    const int j    = blockIdx.x >> 2;
    const int b0   = bch * 64;

    {   // stage LDS-path addends: rows 8j..8j+3 (1024 int4 = 1/thread)
        const int row = tid >> 8, ch = tid & 255;
        const int4 v = ((const int4*)sel0)[(size_t)(8 * j + row) * 256 + ch];
        unsigned* d = &aW[row * 512 + ch * 2];
        d[0] = selpk(v.x, v.y, H_PINF);
        d[1] = selpk(v.z, v.w, H_PINF);
    }

    // slice staging: thread (br, cg) converts 16 f32 -> 2 uint4 (octs 2cg..)
    const int br = tid >> 4, cg = tid & 15;
#define STAGE(T, BUF)                                                        \
    do {                                                                     \
        const float* xr = x + (size_t)(b0 + br) * 1024 + (T) * 256 + cg * 16; \
        const float4 f0 = ((const float4*)xr)[0];                            \
        const float4 f1 = ((const float4*)xr)[1];                            \
        const float4 f2 = ((const float4*)xr)[2];                            \
        const float4 f3 = ((const float4*)xr)[3];                            \
        uint4 w0, w1;                                                        \
        w0.x = hpk(f0.x, f0.y);  w0.y = hpk(f0.z, f0.w);                     \
        w0.z = hpk(f1.x, f1.y);  w0.w = hpk(f1.z, f1.w);                     \
        w1.x = hpk(f2.x, f2.y);  w1.y = hpk(f2.z, f2.w);                     \
        w1.z = hpk(f3.x, f3.y);  w1.w = hpk(f3.z, f3.w);                     \
        xL[BUF][(cg * 2 + 0) * 65 + br] = w0;                                \
        xL[BUF][(cg * 2 + 1) * 65 + br] = w1;                                \
    } while (0)

    STAGE(0, 0);
    __syncthreads();                    // aW + slice 0 ready

    unsigned acc[8];
#pragma unroll
    for (int r = 0; r < 8; ++r) acc[r] = hpk(2.0f, 2.0f);

#pragma unroll
    for (int t = 0; t < 4; ++t) {       // 4 slices of 256 i
        if (t + 1 < 4) STAGE(t + 1, (t + 1) & 1);
        const uint4 xv0 = xL[t & 1][(2 * s + 0) * 65 + lane];
        const uint4 xv1 = xL[t & 1][(2 * s + 1) * 65 + lane];
#pragma unroll
        for (int r = 0; r < 4; ++r) {   // LDS-path rows (uniform ds_read)
            const unsigned* a = &aW[r * 512 + t * 128 + s * 8];
            acc[r] = pk_min(acc[r], pk_add(xv0.x, a[0]));
            acc[r] = pk_min(acc[r], pk_add(xv0.y, a[1]));
            acc[r] = pk_min(acc[r], pk_add(xv0.z, a[2]));
            acc[r] = pk_min(acc[r], pk_add(xv0.w, a[3]));
            acc[r] = pk_min(acc[r], pk_add(xv1.x, a[4]));
            acc[r] = pk_min(acc[r], pk_add(xv1.y, a[5]));
            acc[r] = pk_min(acc[r], pk_add(xv1.z, a[6]));
            acc[r] = pk_min(acc[r], pk_add(xv1.w, a[7]));
        }
#pragma unroll
        for (int r = 0; r < 4; ++r) {   // scalar-path rows (s_load)
            const unsigned* a = &a0h[(size_t)(j * 4 + r) * 512 + t * 128 + s * 8];
            acc[4 + r] = pk_min(acc[4 + r], pk_add(xv0.x, a[0]));
            acc[4 + r] = pk_min(acc[4 + r], pk_add(xv0.y, a[1]));
            acc[4 + r] = pk_min(acc[4 + r], pk_add(xv0.z, a[2]));
            acc[4 + r] = pk_min(acc[4 + r], pk_add(xv0.w, a[3]));
            acc[4 + r] = pk_min(acc[4 + r], pk_add(xv1.x, a[4]));
            acc[4 + r] = pk_min(acc[4 + r], pk_add(xv1.y, a[5]));
            acc[4 + r] = pk_min(acc[4 + r], pk_add(xv1.z, a[6]));
            acc[4 + r] = pk_min(acc[4 + r], pk_add(xv1.w, a[7]));
        }
        __syncthreads();
    }
#undef STAGE

    {   // publish packed pairs: word u = rows (2u | 2u+1), u=0..3
#pragma unroll
        for (int u = 0; u < 4; ++u) {
            const unsigned flo = pk_min(acc[2 * u + 0], acc[2 * u + 0] >> 16);
            const unsigned fhi = pk_min(acc[2 * u + 1], acc[2 * u + 1] >> 16);
            red32[(s * 4 + u) * 64 + lane] = (flo & 0xffffu) | (fhi << 16);
        }
    }
    __syncthreads();

    if (tid < 256) {                    // merge 16 i-chunk partials (paired)
        const int u = tid >> 6, ln = tid & 63;
        unsigned m = red32[u * 64 + ln];
#pragma unroll
        for (int ss = 1; ss < 16; ++ss)
            m = pk_min(m, red32[(ss * 4 + u) * 64 + ln]);
        mrg32[u * 64 + ln] = m;
    }
    __syncthreads();

    if (tid < 64) {                     // uint4 = rows 0..7 paired, in order
        uint4 w;
        w.x = mrg32[0 * 64 + tid];
        w.y = mrg32[1 * 64 + tid];
        w.z = mrg32[2 * 64 + tid];
        w.w = mrg32[3 * 64 + tid];
        hS[(size_t)bch * 4096 + (size_t)j * 64 + tid] = w;
    }
}

// ===== L1: hS + sel1 -> out[256][1024] f32 ===============================
// block = (j2: rows 16j2..+15) x (bch); wave s owns h-octs 4s..4s+3 in
// registers; acc rows 0..7 = LDS addends, 8..15 = scalar path (a1h).
__global__ __launch_bounds__(1024) void daa_l1(
    const uint4* __restrict__ hS, const int* __restrict__ sel1,
    const unsigned* __restrict__ a1h, float* __restrict__ out)
{
    __shared__ unsigned aW[8 * 256];             // rows 16j2..+7, 8 KB
    __shared__ unsigned red32[16 * 8 * 64];      // packed pairs, 32 KB
    __shared__ float redf[16 * 65];              // padded transpose buffer

    const int tid  = threadIdx.x;
    const int lane = tid & 63;
    const int s    = __builtin_amdgcn_readfirstlane(tid >> 6);
    const int bch  = blockIdx.x & 3;
    const int j2   = blockIdx.x >> 2;
    const int b0   = bch * 64;

    {   // stage LDS-path addends: rows 16j2..16j2+7 (1024 int4 = 1/thread)
        const int row = tid >> 7, ch = tid & 127;
        const int4 v = ((const int4*)sel1)[(size_t)(16 * j2 + row) * 128 + ch];
        unsigned* d = &aW[row * 256 + ch * 2];
        d[0] = selpk(v.x, v.y, H_NINF);
        d[1] = selpk(v.z, v.w, H_NINF);
    }

    uint4 xh[4];                         // h-octs 4s..4s+3, read once
#pragma unroll
    for (int k = 0; k < 4; ++k)
        xh[k] = hS[(size_t)bch * 4096 + (size_t)(s * 4 + k) * 64 + lane];

    __syncthreads();

    unsigned acc[16];
#pragma unroll
    for (int r = 0; r < 16; ++r) acc[r] = hpk(-1.0f, -1.0f);

#pragma unroll
    for (int r = 0; r < 8; ++r) {        // LDS-path rows
        const unsigned* a = &aW[r * 256 + s * 16];
#pragma unroll
        for (int k = 0; k < 4; ++k) {
            acc[r] = pk_max(acc[r], pk_add(xh[k].x, a[k * 4 + 0]));
            acc[r] = pk_max(acc[r], pk_add(xh[k].y, a[k * 4 + 1]));
            acc[r] = pk_max(acc[r], pk_add(xh[k].z, a[k * 4 + 2]));
            acc[r] = pk_max(acc[r], pk_add(xh[k].w, a[k * 4 + 3]));
        }
    }
#pragma unroll
    for (int r = 0; r < 8; ++r) {        // scalar-path rows (s_load)
        const unsigned* a = &a1h[(size_t)(j2 * 8 + r) * 256 + s * 16];
#pragma unroll
        for (int k = 0; k < 4; ++k) {
            acc[8 + r] = pk_max(acc[8 + r], pk_add(xh[k].x, a[k * 4 + 0]));
            acc[8 + r] = pk_max(acc[8 + r], pk_add(xh[k].y, a[k * 4 + 1]));
            acc[8 + r] = pk_max(acc[8 + r], pk_add(xh[k].z, a[k * 4 + 2]));
            acc[8 + r] = pk_max(acc[8 + r], pk_add(xh[k].w, a[k * 4 + 3]));
        }
    }

    {   // publish packed pairs: word u = rows (2u | 2u+1), u=0..7
#pragma unroll
        for (int u = 0; u < 8; ++u) {
            const unsigned flo = pk_max(acc[2 * u + 0], acc[2 * u + 0] >> 16);
            const unsigned fhi = pk_max(acc[2 * u + 1], acc[2 * u + 1] >> 16);
            red32[(s * 8 + u) * 64 + lane] = (flo & 0xffffu) | (fhi << 16);
        }
    }
    __syncthreads();

    if (tid < 512) {                     // merge 16 chunk partials (paired)
        const int u = tid >> 6, ln = tid & 63;
        unsigned m = red32[u * 64 + ln];
#pragma unroll
        for (int ss = 1; ss < 16; ++ss)
            m = pk_max(m, red32[(ss * 8 + u) * 64 + ln]);
        redf[(2 * u + 0) * 65 + ln] = h2f((unsigned short)(m & 0xffffu));
        redf[(2 * u + 1) * 65 + ln] = h2f((unsigned short)(m >> 16));
    }
    __syncthreads();

    {   // coalesced store: 64-B segments (4 batches x 16 o per wave)
        const int b = tid >> 4, ol = tid & 15;
        out[(size_t)(b0 + b) * 1024 + 16 * j2 + ol] = redf[ol * 65 + b];
    }
}

extern "C" void kernel_launch(void* const* d_in, const int* in_sizes, int n_in,
                              void* d_out, int out_size, void* d_ws, size_t ws_size,
                              hipStream_t stream) {
    const float* x    = (const float*)d_in[0];  // [256,1024] f32
    const int*   sel0 = (const int*)d_in[1];    // [512,1024] i32
    const int*   sel1 = (const int*)d_in[2];    // [1024,512] i32
    float* out = (float*)d_out;                 // [256,1024] f32

    char* ws = (char*)d_ws;
    uint4*    hS  = (uint4*)ws;                 // 256 KB f16 h slabs
    unsigned* a0h = (unsigned*)(ws + (256 << 10));   // 512 KB scalar addends
    unsigned* a1h = (unsigned*)(ws + (768 << 10));   // 512 KB scalar addends

    pack_sc<<<256, 256, 0, stream>>>(sel0, sel1, a0h, a1h);
    daa_l0<<<256, 1024, 0, stream>>>(x, sel0, a0h, hS);
    daa_l1<<<256, 1024, 0, stream>>>(hS, sel1, a1h, out);
}

// Round 20
// 21.440 us; speedup vs baseline: 1.3592x; 1.3592x over previous
//
#include <hip/hip_runtime.h>
#include <hip/hip_fp16.h>

// DAA autoencoder — R20: R18 register-blocked pipeline (champion, 21.6us)
// + packed-pair partial publish/merge only. R19's dual-path global addends
// regressed +7.5us (likely non-scalarized broadcast loads) and is retired.
//   layer0: h[b][o]   = min_i ( sel0[o][i] ? x[b][i] : 2.0f )
//   layer1: out[b][o] = max_i ( sel1[o][i] ? h[b][i] : -1.0f )
// B=256, IN=1024, HID=512.
//
// Structure (R18): wave owns an i-chunk, updates ALL rows in registers
// (L0: acc[8] over dbuf'd 128-i slices; L1: acc[16], 64KB slab in regs).
// New (R20): partials published as b32 row-pairs -> publish writes halve,
// merge reads halve, L0's final uint4 pack is a direct copy.
//
// Accuracy: identical per-edge values to R15-R18 (f32->f16 RN, +/-inf
// addends, exact offsets; min/max order-independent) => absmax 1.22e-4.

#define H_PINF 0x7C00u
#define H_NINF 0xFC00u

__device__ __forceinline__ unsigned pk_add(unsigned a, unsigned b) {
    unsigned r; asm("v_pk_add_f16 %0, %1, %2" : "=v"(r) : "v"(a), "v"(b)); return r;
}
__device__ __forceinline__ unsigned pk_min(unsigned a, unsigned b) {
    unsigned r; asm("v_pk_min_f16 %0, %1, %2" : "=v"(r) : "v"(a), "v"(b)); return r;
}
__device__ __forceinline__ unsigned pk_max(unsigned a, unsigned b) {
    unsigned r; asm("v_pk_max_f16 %0, %1, %2" : "=v"(r) : "v"(a), "v"(b)); return r;
}
__device__ __forceinline__ unsigned hpk(float a, float b) {
    return (unsigned)__half_as_ushort(__float2half(a))
         | ((unsigned)__half_as_ushort(__float2half(b)) << 16);
}
__device__ __forceinline__ float h2f(unsigned short u) {
    __half h = *reinterpret_cast<__half*>(&u);
    return __half2float(h);
}
__device__ __forceinline__ unsigned selpk(int a, int b, unsigned inf) {
    return (a ? 0u : inf) | ((b ? 0u : inf) << 16);
}

// ===== L0: x[256][1024] f32 + sel0 -> hS[4][64][64] uint4 f16 slabs ======
// block = (j = o-oct) x (bch); 16 waves. Wave s owns i-oct s of each of 8
// 128-i slices and updates all 8 rows (acc[8]).
__global__ __launch_bounds__(1024) void daa_l0(
    const float* __restrict__ x, const int* __restrict__ sel0,
    uint4* __restrict__ hS)
{
    __shared__ unsigned aW[8 * 512];            // 8 rows x 1024 halves, 16 KB
    __shared__ uint4 xL[2][16 * 65];            // dbuf slice, 2 x 16.25 KB
    __shared__ unsigned red32[16 * 4 * 64];     // packed row-pairs, 16 KB
    __shared__ unsigned mrg32[4 * 64];          // merged pairs, 1 KB

    const int tid  = threadIdx.x;
    const int lane = tid & 63;
    const int s    = __builtin_amdgcn_readfirstlane(tid >> 6);
    const int bch  = blockIdx.x & 3;
    const int j    = blockIdx.x >> 2;           // o rows 8j..8j+7
    const int b0   = bch * 64;

    {   // stage sel0 rows 8j..8j+7 as packed f16 addends
        const int4* sp = (const int4*)sel0;     // [512 rows][256 int4]
        const int row = tid >> 7, ch = tid & 127;
        const int4 v0 = sp[(size_t)(8 * j + row) * 256 + ch * 2 + 0];
        const int4 v1 = sp[(size_t)(8 * j + row) * 256 + ch * 2 + 1];
        unsigned* dst = &aW[row * 512 + ch * 4];
        dst[0] = selpk(v0.x, v0.y, H_PINF);
        dst[1] = selpk(v0.z, v0.w, H_PINF);
        dst[2] = selpk(v1.x, v1.y, H_PINF);
        dst[3] = selpk(v1.z, v1.w, H_PINF);
    }

    // slice staging: thread (br = batch row, cg = oct) converts 8 f32 -> f16
    const int br = tid >> 4, cg = tid & 15;
#define STAGE(T, BUF)                                                      \
    do {                                                                   \
        const float* xr = x + (size_t)(b0 + br) * 1024 + (T) * 128 + cg * 8; \
        const float4 f0 = ((const float4*)xr)[0];                          \
        const float4 f1 = ((const float4*)xr)[1];                          \
        uint4 w;                                                           \
        w.x = hpk(f0.x, f0.y);  w.y = hpk(f0.z, f0.w);                     \
        w.z = hpk(f1.x, f1.y);  w.w = hpk(f1.z, f1.w);                     \
        xL[BUF][cg * 65 + br] = w;                                         \
    } while (0)

    STAGE(0, 0);
    __syncthreads();                    // aW + slice 0 ready

    unsigned acc[8];
#pragma unroll
    for (int r = 0; r < 8; ++r) acc[r] = hpk(2.0f, 2.0f);

#pragma unroll
    for (int t = 0; t < 8; ++t) {
        if (t + 1 < 8) STAGE(t + 1, (t + 1) & 1);   // overlap with compute
        const uint4 xv = xL[t & 1][s * 65 + lane];  // read ONCE, 8 rows use
#pragma unroll
        for (int r = 0; r < 8; ++r) {
            const unsigned* a = &aW[r * 512 + t * 64 + s * 4];  // uniform
            acc[r] = pk_min(acc[r], pk_add(xv.x, a[0]));
            acc[r] = pk_min(acc[r], pk_add(xv.y, a[1]));
            acc[r] = pk_min(acc[r], pk_add(xv.z, a[2]));
            acc[r] = pk_min(acc[r], pk_add(xv.w, a[3]));
        }
        __syncthreads();                // next slice staged + reads done
    }
#undef STAGE

    {   // publish packed pairs: word u = rows (2u lo | 2u+1 hi)
#pragma unroll
        for (int u = 0; u < 4; ++u) {
            const unsigned flo = pk_min(acc[2 * u + 0], acc[2 * u + 0] >> 16);
            const unsigned fhi = pk_min(acc[2 * u + 1], acc[2 * u + 1] >> 16);
            red32[(s * 4 + u) * 64 + lane] = (flo & 0xffffu) | (fhi << 16);
        }
    }
    __syncthreads();

    if (tid < 256) {                    // merge 16 i-chunk partials (paired)
        const int u = tid >> 6, ln = tid & 63;
        unsigned m = red32[u * 64 + ln];
#pragma unroll
        for (int ss = 1; ss < 16; ++ss)
            m = pk_min(m, red32[(ss * 4 + u) * 64 + ln]);
        mrg32[u * 64 + ln] = m;
    }
    __syncthreads();

    if (tid < 64) {                     // uint4 = 4 packed pairs, in order
        uint4 w;
        w.x = mrg32[0 * 64 + tid];      // rows 0,1
        w.y = mrg32[1 * 64 + tid];      // rows 2,3
        w.z = mrg32[2 * 64 + tid];      // rows 4,5
        w.w = mrg32[3 * 64 + tid];      // rows 6,7
        hS[(size_t)bch * 4096 + (size_t)j * 64 + tid] = w;
    }
}

// ===== L1: hS slabs + sel1 -> out[256][1024] f32 =========================
// block = (j2: rows 16j2..+15) x (bch); wave s owns h-octs 4s..4s+3 in
// registers (slab read once per block) and updates all 16 rows (acc[16]).
__global__ __launch_bounds__(1024) void daa_l1(
    const uint4* __restrict__ hS, const int* __restrict__ sel1,
    float* __restrict__ out)
{
    __shared__ unsigned aW[16 * 256];            // 16 rows x 512 halves, 16 KB
    __shared__ unsigned red32[16 * 8 * 64];      // packed row-pairs, 32 KB
    __shared__ float redf[16 * 65];              // padded transpose buffer

    const int tid  = threadIdx.x;
    const int lane = tid & 63;
    const int s    = __builtin_amdgcn_readfirstlane(tid >> 6);
    const int bch  = blockIdx.x & 3;
    const int j2   = blockIdx.x >> 2;
    const int b0   = bch * 64;

    {   // stage sel1 rows 16j2..16j2+15 as packed addends
        const int4* sp = (const int4*)sel1;      // [1024 rows][128 int4]
        const int row = tid >> 6, ch = tid & 63;
        const int4 v0 = sp[(size_t)(16 * j2 + row) * 128 + ch * 2 + 0];
        const int4 v1 = sp[(size_t)(16 * j2 + row) * 128 + ch * 2 + 1];
        unsigned* dst = &aW[row * 256 + ch * 4];
        dst[0] = selpk(v0.x, v0.y, H_NINF);
        dst[1] = selpk(v0.z, v0.w, H_NINF);
        dst[2] = selpk(v1.x, v1.y, H_NINF);
        dst[3] = selpk(v1.z, v1.w, H_NINF);
    }

    // h-chunk into registers: octs 4s..4s+3 (32 h-values/lane, 16 VGPRs)
    uint4 xh[4];
#pragma unroll
    for (int k = 0; k < 4; ++k)
        xh[k] = hS[(size_t)bch * 4096 + (size_t)(s * 4 + k) * 64 + lane];

    __syncthreads();                    // aW ready

    unsigned acc[16];
#pragma unroll
    for (int r = 0; r < 16; ++r) acc[r] = hpk(-1.0f, -1.0f);

#pragma unroll
    for (int r = 0; r < 16; ++r) {
        const unsigned* a = &aW[r * 256 + s * 16];      // uniform
#pragma unroll
        for (int k = 0; k < 4; ++k) {
            acc[r] = pk_max(acc[r], pk_add(xh[k].x, a[k * 4 + 0]));
            acc[r] = pk_max(acc[r], pk_add(xh[k].y, a[k * 4 + 1]));
            acc[r] = pk_max(acc[r], pk_add(xh[k].z, a[k * 4 + 2]));
            acc[r] = pk_max(acc[r], pk_add(xh[k].w, a[k * 4 + 3]));
        }
    }

    {   // publish packed pairs: word u = rows (2u lo | 2u+1 hi), u=0..7
#pragma unroll
        for (int u = 0; u < 8; ++u) {
            const unsigned flo = pk_max(acc[2 * u + 0], acc[2 * u + 0] >> 16);
            const unsigned fhi = pk_max(acc[2 * u + 1], acc[2 * u + 1] >> 16);
            red32[(s * 8 + u) * 64 + lane] = (flo & 0xffffu) | (fhi << 16);
        }
    }
    __syncthreads();

    if (tid < 512) {                     // merge 16 chunk partials (paired)
        const int u = tid >> 6, ln = tid & 63;
        unsigned m = red32[u * 64 + ln];
#pragma unroll
        for (int ss = 1; ss < 16; ++ss)
            m = pk_max(m, red32[(ss * 8 + u) * 64 + ln]);
        redf[(2 * u + 0) * 65 + ln] = h2f((unsigned short)(m & 0xffffu));
        redf[(2 * u + 1) * 65 + ln] = h2f((unsigned short)(m >> 16));
    }
    __syncthreads();

    {   // coalesced store: 64-B segments (4 batches x 16 o per wave)
        const int b = tid >> 4, ol = tid & 15;
        out[(size_t)(b0 + b) * 1024 + 16 * j2 + ol] = redf[ol * 65 + b];
    }
}

extern "C" void kernel_launch(void* const* d_in, const int* in_sizes, int n_in,
                              void* d_out, int out_size, void* d_ws, size_t ws_size,
                              hipStream_t stream) {
    const float* x    = (const float*)d_in[0];  // [256,1024] f32
    const int*   sel0 = (const int*)d_in[1];    // [512,1024] i32
    const int*   sel1 = (const int*)d_in[2];    // [1024,512] i32
    float* out = (float*)d_out;                 // [256,1024] f32

    uint4* hS = (uint4*)d_ws;                   // 256 KB f16 h slabs

    daa_l0<<<256, 1024, 0, stream>>>(x, sel0, hS);
    daa_l1<<<256, 1024, 0, stream>>>(hS, sel1, out);
}